// Round 13
// baseline (259.308 us; speedup 1.0000x reference)
//
#include <hip/hip_runtime.h>
#include <cstdint>
#include <cstddef>

#define EPS 1e-5f
#define CAP 64
#define CHUNK 4096
#define NBMAX 256

typedef __attribute__((ext_vector_type(8))) short short8;
typedef __attribute__((ext_vector_type(4))) float f32x4;

static __device__ __forceinline__ short f2bf(float f) {
    uint32_t u = __float_as_uint(f);
    u += 0x7FFFu + ((u >> 16) & 1u);
    return (short)(u >> 16);
}
static __device__ __forceinline__ float bf2f(short s) {
    return __uint_as_float(((uint32_t)(uint16_t)s) << 16);
}

// ---- kernel 1 (fused, block-specialized):
//   [0,BB)       dst-bucket edges (int2 {src,dst}) into breg   [reg-staged]
//   [BB,BB+SB)   src-bucket edges (int src) into sbreg          [reg-staged]
//   [..,+TB)     x -> bf16
//   [..,+64)     WT build
__global__ __launch_bounds__(256) void k_prep(
        const int* __restrict__ src, const int* __restrict__ dst, int E,
        const float* __restrict__ x, const float* __restrict__ W,
        int* __restrict__ bcur, int2* __restrict__ breg,
        int* __restrict__ sbcur, int* __restrict__ sbreg,
        int REGCAP, int NBK, short* __restrict__ xbf, short* __restrict__ WT,
        int BB, int SB, int TB, int t8) {
    int b = blockIdx.x;
    int t = threadIdx.x;
    __shared__ int hist[NBMAX], sexc[NBMAX], cur[NBMAX], gb[NBMAX];
    __shared__ int wsum[4];
    __shared__ int2 stage[CHUNK];
    if (b < BB) {
        int e0 = b * CHUNK;
        int2 ed[16];
        #pragma unroll
        for (int k = 0; k < 16; ++k) {
            int i = e0 + k * 256 + t;
            ed[k].x = (i < E) ? src[i] : 0;
            ed[k].y = (i < E) ? dst[i] : -1;
        }
        hist[t] = 0;
        __syncthreads();
        #pragma unroll
        for (int k = 0; k < 16; ++k)
            if (ed[k].y >= 0) atomicAdd(&hist[ed[k].y >> 9], 1);
        __syncthreads();
        int lane = t & 63, wv = t >> 6;
        int val = hist[t];
        int incl = val;
        #pragma unroll
        for (int off = 1; off < 64; off <<= 1) {
            int v = __shfl_up(incl, off);
            if (lane >= off) incl += v;
        }
        if (lane == 63) wsum[wv] = incl;
        __syncthreads();
        int bw = 0;
        for (int r = 0; r < wv; ++r) bw += wsum[r];
        int excl = bw + incl - val;
        sexc[t] = excl;
        cur[t] = excl;
        gb[t] = (val > 0 && t < NBK) ? atomicAdd(&bcur[t], val) : 0;
        __syncthreads();
        #pragma unroll
        for (int k = 0; k < 16; ++k) {
            if (ed[k].y >= 0) {
                int p = atomicAdd(&cur[ed[k].y >> 9], 1);
                stage[p] = ed[k];
            }
        }
        __syncthreads();
        int C = E - e0; if (C > CHUNK) C = CHUNK;
        for (int idx = t; idx < C; idx += 256) {
            int2 e = stage[idx];
            int bb = e.y >> 9;
            int pos = gb[bb] + (idx - sexc[bb]);
            if (pos < REGCAP) breg[(size_t)bb * REGCAP + pos] = e;
        }
    } else if (b < BB + SB) {
        int* sstage = (int*)stage;
        int e0 = (b - BB) * CHUNK;
        int es[16];
        #pragma unroll
        for (int k = 0; k < 16; ++k) {
            int i = e0 + k * 256 + t;
            es[k] = (i < E) ? src[i] : -1;
        }
        hist[t] = 0;
        __syncthreads();
        #pragma unroll
        for (int k = 0; k < 16; ++k)
            if (es[k] >= 0) atomicAdd(&hist[es[k] >> 9], 1);
        __syncthreads();
        int lane = t & 63, wv = t >> 6;
        int val = hist[t];
        int incl = val;
        #pragma unroll
        for (int off = 1; off < 64; off <<= 1) {
            int v = __shfl_up(incl, off);
            if (lane >= off) incl += v;
        }
        if (lane == 63) wsum[wv] = incl;
        __syncthreads();
        int bw = 0;
        for (int r = 0; r < wv; ++r) bw += wsum[r];
        int excl = bw + incl - val;
        sexc[t] = excl;
        cur[t] = excl;
        gb[t] = (val > 0 && t < NBK) ? atomicAdd(&sbcur[t], val) : 0;
        __syncthreads();
        #pragma unroll
        for (int k = 0; k < 16; ++k) {
            if (es[k] >= 0) {
                int p = atomicAdd(&cur[es[k] >> 9], 1);
                sstage[p] = es[k];
            }
        }
        __syncthreads();
        int C = E - e0; if (C > CHUNK) C = CHUNK;
        for (int idx = t; idx < C; idx += 256) {
            int s = sstage[idx];
            int bb = s >> 9;
            int pos = gb[bb] + (idx - sexc[bb]);
            if (pos < REGCAP) sbreg[(size_t)bb * REGCAP + pos] = s;
        }
    } else if (b < BB + SB + TB) {
        int i = (b - BB - SB) * 256 + t;
        if (i < t8) {
            const float4* s = (const float4*)x + (size_t)i * 2;
            float4 a = s[0], bb4 = s[1];
            short8 o;
            o[0] = f2bf(a.x); o[1] = f2bf(a.y); o[2] = f2bf(a.z); o[3] = f2bf(a.w);
            o[4] = f2bf(bb4.x); o[5] = f2bf(bb4.y); o[6] = f2bf(bb4.z); o[7] = f2bf(bb4.w);
            ((short8*)xbf)[i] = o;
        }
    } else {
        int i = (b - BB - SB - TB) * 256 + t;
        if (i < 16384) {
            int k = i >> 7, c = i & 127;
            float w0 = W[i], w1 = W[16384 + i], w2 = W[32768 + i];
            WT[(size_t)c * 384 + k]       = f2bf(w0 - w2);
            WT[(size_t)c * 384 + 128 + k] = f2bf(w1);
            WT[(size_t)c * 384 + 256 + k] = f2bf(2.f * w2);
        }
    }
}

// ---- kernel 2: per-bucket CSR build + deg histogram (all LDS atomics) + cnt + dinv ----
__global__ __launch_bounds__(256) void k_csr(
        const int2* __restrict__ breg, const int* __restrict__ bcur,
        const int* __restrict__ sbreg, const int* __restrict__ sbcur,
        int REGCAP, int n,
        int* __restrict__ slots, int* __restrict__ cnt, float* __restrict__ dinv) {
    int b = blockIdx.x, t = threadIdx.x;
    __shared__ int c512[512], d512[512];
    c512[t] = 0; c512[t + 256] = 0;
    d512[t] = 0; d512[t + 256] = 0;
    __syncthreads();
    int M2 = sbcur[b]; if (M2 > REGCAP) M2 = REGCAP;
    const int* sreg = sbreg + (size_t)b * REGCAP;
    for (int idx = t; idx < M2; idx += 256)
        atomicAdd(&d512[sreg[idx] & 511], 1);
    int M = bcur[b]; if (M > REGCAP) M = REGCAP;
    const int2* reg = breg + (size_t)b * REGCAP;
    for (int idx = t; idx < M; idx += 256) {
        int2 e = reg[idx];
        int p = atomicAdd(&c512[e.y & 511], 1);
        if (p < CAP) slots[(size_t)e.y * CAP + p] = e.x;
    }
    __syncthreads();
    #pragma unroll
    for (int i = t; i < 512; i += 256) {
        int node = (b << 9) + i;
        if (node < n) {
            int c = c512[i];
            cnt[node] = c > CAP ? CAP : c;
            float dd = (float)d512[i];
            dinv[node] = dd > 0.f ? rsqrtf(dd) : 0.f;
        }
    }
}

// ---- kernel 3: lhat gather (R10 body: j+=8, 2 gathers in flight per 16-lane group) ----
__global__ void k_gather_slots(const short* __restrict__ vbf, const int* __restrict__ cnt,
                               const int* __restrict__ slots, const float* __restrict__ dinv,
                               short* __restrict__ outp, int n) {
    int row = blockIdx.x * 4 + (threadIdx.x >> 6);
    if (row >= n) return;
    int lane = threadIdx.x & 63;
    int gr = lane >> 4, lc = lane & 15;
    int deg = cnt[row];
    bool vl = lane < deg;
    int   sl = vl ? slots[(size_t)row * CAP + lane] : 0;
    float wv = vl ? dinv[sl] : 0.f;
    float acc[8];
    #pragma unroll
    for (int t = 0; t < 8; ++t) acc[t] = 0.f;
    #pragma unroll 2
    for (int j = 0; j < deg; j += 8) {
        int j0 = j + gr, j1 = j + gr + 4;
        int   s0 = __shfl(sl, j0), s1 = __shfl(sl, j1);
        float w0 = __shfl(wv, j0), w1 = __shfl(wv, j1);
        short8 xv0 = *(const short8*)(vbf + (size_t)s0 * 128 + lc * 8);
        short8 xv1 = *(const short8*)(vbf + (size_t)s1 * 128 + lc * 8);
        #pragma unroll
        for (int t = 0; t < 8; ++t) {
            acc[t] = fmaf(w0, bf2f(xv0[t]), acc[t]);
            acc[t] = fmaf(w1, bf2f(xv1[t]), acc[t]);
        }
    }
    #pragma unroll
    for (int t = 0; t < 8; ++t) {
        acc[t] += __shfl_xor(acc[t], 32);
        acc[t] += __shfl_xor(acc[t], 16);
    }
    if (gr == 0) {
        float sc = -dinv[row];
        short8 o;
        #pragma unroll
        for (int t = 0; t < 8; ++t) o[t] = f2bf(sc * acc[t]);
        *(short8*)(outp + (size_t)row * 128 + lc * 8) = o;
    }
}

// ---- kernel 4: bf16 MFMA GEMM, BM=64; A staged via gload_lds, B read DIRECT from L2 ----
// LDS 8 KB -> 8 blocks/CU. out = [x|tx1|tx2] @ Weff + bias, PReLU; BN partials stored.
__global__ __launch_bounds__(256) void k_gemm_mfma(
        const short* __restrict__ A0bf, const short* __restrict__ A1bf,
        const short* __restrict__ A2bf,
        const short* __restrict__ WT, const float* __restrict__ bias,
        const float* __restrict__ aprelu, float* __restrict__ out,
        float* __restrict__ partials, int NB, int n) {
    __shared__ __align__(16) short Alds[64 * 64];    // 8 KB

    int t = threadIdx.x;
    int lane = t & 63;
    int w = t >> 6;
    int wr = w >> 1, wc = w & 1;
    int row0 = blockIdx.x * 64;

    f32x4 acc[2][4];
    #pragma unroll
    for (int m = 0; m < 2; ++m)
        #pragma unroll
        for (int nn = 0; nn < 4; ++nn) acc[m][nn] = (f32x4){0.f, 0.f, 0.f, 0.f};

    #pragma unroll
    for (int ht = 0; ht < 6; ++ht) {
        const int h = ht >> 1, c = ht & 1;
        const short* Abf = (h == 0) ? A0bf : (h == 1) ? A1bf : A2bf;

        if (ht) __syncthreads();   // previous phase's Alds reads complete

        // stage A tile: 64 rows x 64 k, 2 issues/wave
        #pragma unroll
        for (int i = 0; i < 2; ++i) {
            int rA = w * 16 + i * 8 + (lane >> 3);
            int grow = row0 + rA; if (grow >= n) grow = n - 1;
            int blkA = (lane & 7) ^ (rA & 7);
            const short* srcA = Abf + (size_t)grow * 128 + c * 64 + blkA * 8;
            __builtin_amdgcn_global_load_lds(
                (const __attribute__((address_space(1))) void*)srcA,
                (__attribute__((address_space(3))) void*)&Alds[(w * 16 + i * 8) * 64],
                16, 0, 0);
        }
        __syncthreads();

        #pragma unroll
        for (int kk = 0; kk < 2; ++kk) {
            int jl = kk * 4 + (lane >> 4);
            short8 af[2], bfr[4];
            #pragma unroll
            for (int m = 0; m < 2; ++m) {
                int row = wr * 32 + m * 16 + (lane & 15);
                int blk = jl ^ (row & 7);
                af[m] = *(const short8*)((const char*)Alds + row * 128 + blk * 16);
            }
            #pragma unroll
            for (int nn = 0; nn < 4; ++nn) {
                int col = wc * 64 + nn * 16 + (lane & 15);
                bfr[nn] = *(const short8*)(WT + (size_t)col * 384 + h * 128 + c * 64 + jl * 8);
            }
            #pragma unroll
            for (int m = 0; m < 2; ++m)
                #pragma unroll
                for (int nn = 0; nn < 4; ++nn)
                    acc[m][nn] = __builtin_amdgcn_mfma_f32_16x16x32_bf16(
                        af[m], bfr[nn], acc[m][nn], 0, 0, 0);
        }
    }

    __syncthreads();
    float* sred = (float*)Alds;      // [0..127]=sum, [128..255]=sumsq
    sred[t < 256 ? t : 0] = 0.f;
    __syncthreads();

    float ap = aprelu[0];
    #pragma unroll
    for (int nn = 0; nn < 4; ++nn) {
        int col = wc * 64 + nn * 16 + (lane & 15);
        float bs = bias[col];
        float s = 0.f, q = 0.f;
        #pragma unroll
        for (int m = 0; m < 2; ++m) {
            int rbase = row0 + wr * 32 + m * 16 + (lane >> 4) * 4;
            #pragma unroll
            for (int r = 0; r < 4; ++r) {
                int row = rbase + r;
                if (row < n) {
                    float o = acc[m][nn][r] + bs;
                    o = o >= 0.f ? o : ap * o;
                    out[(size_t)row * 128 + col] = o;
                    s += o; q = fmaf(o, o, q);
                }
            }
        }
        s += __shfl_xor(s, 16); s += __shfl_xor(s, 32);
        q += __shfl_xor(q, 16); q += __shfl_xor(q, 32);
        if ((lane >> 4) == 0) {
            atomicAdd(&sred[col], s);
            atomicAdd(&sred[128 + col], q);
        }
    }
    __syncthreads();
    if (t < 256) partials[(size_t)t * NB + blockIdx.x] = sred[t];
}

// ---- kernel 5: reduce partials -> sums/sumsq ----
__global__ __launch_bounds__(256) void k_redstats(
        const float* __restrict__ partials, int NB,
        float* __restrict__ sums, float* __restrict__ sumsq) {
    int j = blockIdx.x, t = threadIdx.x;
    const float* p = partials + (size_t)j * NB;
    float s = 0.f;
    for (int i = t; i < NB; i += 256) s += p[i];
    s += __shfl_xor(s, 1); s += __shfl_xor(s, 2); s += __shfl_xor(s, 4);
    s += __shfl_xor(s, 8); s += __shfl_xor(s, 16); s += __shfl_xor(s, 32);
    __shared__ float wsum[4];
    if ((t & 63) == 0) wsum[t >> 6] = s;
    __syncthreads();
    if (t == 0) {
        float tot = wsum[0] + wsum[1] + wsum[2] + wsum[3];
        if (j < 128) sums[j] = tot;
        else sumsq[j - 128] = tot;
    }
}

// ---- kernel 6: BN scale/shift from stats ----
__global__ void k_bnfinal(const float* __restrict__ sums, const float* __restrict__ sumsq,
                          const float* __restrict__ gamma, const float* __restrict__ beta,
                          float* __restrict__ bnp, float n) {
    int c = threadIdx.x;
    float mean = sums[c] / n;
    float var = sumsq[c] / n - mean * mean;
    float sc = gamma[c] * rsqrtf(var + EPS);
    bnp[c] = sc;
    bnp[128 + c] = beta[c] - mean * sc;
}

// ---- kernel 7: apply BN in place ----
__global__ void k_bnapply(float* __restrict__ out, const float* __restrict__ bnp, int total4) {
    int i = blockIdx.x * blockDim.x + threadIdx.x;
    if (i >= total4) return;
    float4 v = ((float4*)out)[i];
    int c = (i * 4) & 127;
    float4 sc = *(const float4*)&bnp[c];
    float4 sh = *(const float4*)&bnp[128 + c];
    v.x = fmaf(v.x, sc.x, sh.x);
    v.y = fmaf(v.y, sc.y, sh.y);
    v.z = fmaf(v.z, sc.z, sh.z);
    v.w = fmaf(v.w, sc.w, sh.w);
    ((float4*)out)[i] = v;
}

extern "C" void kernel_launch(void* const* d_in, const int* in_sizes, int n_in,
                              void* d_out, int out_size, void* d_ws, size_t ws_size,
                              hipStream_t stream) {
    const float* x      = (const float*)d_in[0];
    const int*   ei     = (const int*)d_in[1];
    const float* W      = (const float*)d_in[2];
    const float* bias   = (const float*)d_in[3];
    const float* aprelu = (const float*)d_in[4];
    const float* gamma  = (const float*)d_in[5];
    const float* beta   = (const float*)d_in[6];
    int n = in_sizes[0] / 128;
    int E = in_sizes[1] / 2;
    const int* srcp = ei;
    const int* dstp = ei + E;

    int NBK = (n + 511) >> 9;
    int REGCAP = ((E / NBK) * 2 + 255) & ~255;
    int mb = (n + 63) / 64;

    char* ws = (char*)d_ws;
    size_t off = 0;
    auto carve = [&](size_t bytes) {
        char* p = ws + off;
        off = (off + bytes + 511) & ~(size_t)511;
        return p;
    };
    short* xbf   = (short*)carve((size_t)n * 128 * 2);
    short* tx1bf = (short*)carve((size_t)n * 128 * 2);   // aliases sbreg (disjoint lifetime)
    int*   sbreg = (int*)tx1bf;
    size_t bregsz = (size_t)NBK * REGCAP * 8;
    size_t tx2sz  = (size_t)n * 128 * 2;
    char*  bregp  = carve(bregsz > tx2sz ? bregsz : tx2sz);
    int2*  breg   = (int2*)bregp;                        // live: k_prep..k_csr
    short* tx2bf  = (short*)bregp;                       // live: gather2..gemm (aliased)
    size_t zbeg = off;
    int*   bcur  = (int*)carve(NBMAX * 4);
    int*   sbcur = (int*)carve(NBMAX * 4);
    size_t zend = off;
    float* sums  = (float*)carve(512);
    float* sumsq = (float*)carve(512);
    float* dinv  = (float*)carve((size_t)n * 4);
    int*   cnt   = (int*)carve((size_t)n * 4);
    int*   slots = (int*)carve((size_t)n * CAP * 4);
    short* WT    = (short*)carve((size_t)128 * 384 * 2);
    float* bnp   = (float*)carve(256 * 4);
    float* partials = (float*)carve((size_t)256 * mb * 4);
    (void)ws_size; (void)n_in; (void)out_size;

    hipMemsetAsync(ws + zbeg, 0, zend - zbeg, stream);

    int BB = (E + CHUNK - 1) / CHUNK;
    int SB = BB;
    int t8 = n * 16;
    int TB = (t8 + 255) / 256;
    k_prep<<<BB + SB + TB + 64, 256, 0, stream>>>(srcp, dstp, E, x, W, bcur, breg,
                                                  sbcur, sbreg, REGCAP, NBK, xbf, WT,
                                                  BB, SB, TB, t8);
    k_csr<<<NBK, 256, 0, stream>>>(breg, bcur, sbreg, sbcur, REGCAP, n, slots, cnt, dinv);
    int gb = (n + 3) / 4;
    k_gather_slots<<<gb, 256, 0, stream>>>(xbf, cnt, slots, dinv, tx1bf, n);
    k_gather_slots<<<gb, 256, 0, stream>>>(tx1bf, cnt, slots, dinv, tx2bf, n);
    k_gemm_mfma<<<mb, 256, 0, stream>>>(xbf, tx1bf, tx2bf, WT, bias, aprelu, (float*)d_out,
                                        partials, mb, n);
    k_redstats<<<256, 256, 0, stream>>>(partials, mb, sums, sumsq);
    k_bnfinal<<<1, 128, 0, stream>>>(sums, sumsq, gamma, beta, bnp, (float)n);
    int total4 = n * 32;
    k_bnapply<<<(total4 + 255) / 256, 256, 0, stream>>>((float*)d_out, bnp, total4);
}

// Round 15
// 231.674 us; speedup vs baseline: 1.1193x; 1.1193x over previous
//
#include <hip/hip_runtime.h>
#include <cstdint>
#include <cstddef>

#define EPS 1e-5f
#define CAP 64
#define CHUNK 4096
#define NBMAX 256

typedef __attribute__((ext_vector_type(8))) short short8;
typedef __attribute__((ext_vector_type(4))) float f32x4;

static __device__ __forceinline__ short f2bf(float f) {
    uint32_t u = __float_as_uint(f);
    u += 0x7FFFu + ((u >> 16) & 1u);
    return (short)(u >> 16);
}
static __device__ __forceinline__ float bf2f(short s) {
    return __uint_as_float(((uint32_t)(uint16_t)s) << 16);
}

// ---- kernel 1 (fused, block-specialized):
//   [0,BB)       dst-bucket edges (int2 {src,dst}) into breg   [reg-staged]
//   [BB,BB+SB)   src-bucket edges (int src) into sbreg          [reg-staged]
//   [..,+TB)     x -> bf16
//   [..,+64)     WT build
__global__ __launch_bounds__(256) void k_prep(
        const int* __restrict__ src, const int* __restrict__ dst, int E,
        const float* __restrict__ x, const float* __restrict__ W,
        int* __restrict__ bcur, int2* __restrict__ breg,
        int* __restrict__ sbcur, int* __restrict__ sbreg,
        int REGCAP, int NBK, short* __restrict__ xbf, short* __restrict__ WT,
        int BB, int SB, int TB, int t8) {
    int b = blockIdx.x;
    int t = threadIdx.x;
    __shared__ int hist[NBMAX], sexc[NBMAX], cur[NBMAX], gb[NBMAX];
    __shared__ int wsum[4];
    __shared__ int2 stage[CHUNK];
    if (b < BB) {
        int e0 = b * CHUNK;
        int2 ed[16];
        #pragma unroll
        for (int k = 0; k < 16; ++k) {
            int i = e0 + k * 256 + t;
            ed[k].x = (i < E) ? src[i] : 0;
            ed[k].y = (i < E) ? dst[i] : -1;
        }
        hist[t] = 0;
        __syncthreads();
        #pragma unroll
        for (int k = 0; k < 16; ++k)
            if (ed[k].y >= 0) atomicAdd(&hist[ed[k].y >> 9], 1);
        __syncthreads();
        int lane = t & 63, wv = t >> 6;
        int val = hist[t];
        int incl = val;
        #pragma unroll
        for (int off = 1; off < 64; off <<= 1) {
            int v = __shfl_up(incl, off);
            if (lane >= off) incl += v;
        }
        if (lane == 63) wsum[wv] = incl;
        __syncthreads();
        int bw = 0;
        for (int r = 0; r < wv; ++r) bw += wsum[r];
        int excl = bw + incl - val;
        sexc[t] = excl;
        cur[t] = excl;
        gb[t] = (val > 0 && t < NBK) ? atomicAdd(&bcur[t], val) : 0;
        __syncthreads();
        #pragma unroll
        for (int k = 0; k < 16; ++k) {
            if (ed[k].y >= 0) {
                int p = atomicAdd(&cur[ed[k].y >> 9], 1);
                stage[p] = ed[k];
            }
        }
        __syncthreads();
        int C = E - e0; if (C > CHUNK) C = CHUNK;
        for (int idx = t; idx < C; idx += 256) {
            int2 e = stage[idx];
            int bb = e.y >> 9;
            int pos = gb[bb] + (idx - sexc[bb]);
            if (pos < REGCAP) breg[(size_t)bb * REGCAP + pos] = e;
        }
    } else if (b < BB + SB) {
        int* sstage = (int*)stage;
        int e0 = (b - BB) * CHUNK;
        int es[16];
        #pragma unroll
        for (int k = 0; k < 16; ++k) {
            int i = e0 + k * 256 + t;
            es[k] = (i < E) ? src[i] : -1;
        }
        hist[t] = 0;
        __syncthreads();
        #pragma unroll
        for (int k = 0; k < 16; ++k)
            if (es[k] >= 0) atomicAdd(&hist[es[k] >> 9], 1);
        __syncthreads();
        int lane = t & 63, wv = t >> 6;
        int val = hist[t];
        int incl = val;
        #pragma unroll
        for (int off = 1; off < 64; off <<= 1) {
            int v = __shfl_up(incl, off);
            if (lane >= off) incl += v;
        }
        if (lane == 63) wsum[wv] = incl;
        __syncthreads();
        int bw = 0;
        for (int r = 0; r < wv; ++r) bw += wsum[r];
        int excl = bw + incl - val;
        sexc[t] = excl;
        cur[t] = excl;
        gb[t] = (val > 0 && t < NBK) ? atomicAdd(&sbcur[t], val) : 0;
        __syncthreads();
        #pragma unroll
        for (int k = 0; k < 16; ++k) {
            if (es[k] >= 0) {
                int p = atomicAdd(&cur[es[k] >> 9], 1);
                sstage[p] = es[k];
            }
        }
        __syncthreads();
        int C = E - e0; if (C > CHUNK) C = CHUNK;
        for (int idx = t; idx < C; idx += 256) {
            int s = sstage[idx];
            int bb = s >> 9;
            int pos = gb[bb] + (idx - sexc[bb]);
            if (pos < REGCAP) sbreg[(size_t)bb * REGCAP + pos] = s;
        }
    } else if (b < BB + SB + TB) {
        int i = (b - BB - SB) * 256 + t;
        if (i < t8) {
            const float4* s = (const float4*)x + (size_t)i * 2;
            float4 a = s[0], bb4 = s[1];
            short8 o;
            o[0] = f2bf(a.x); o[1] = f2bf(a.y); o[2] = f2bf(a.z); o[3] = f2bf(a.w);
            o[4] = f2bf(bb4.x); o[5] = f2bf(bb4.y); o[6] = f2bf(bb4.z); o[7] = f2bf(bb4.w);
            ((short8*)xbf)[i] = o;
        }
    } else {
        int i = (b - BB - SB - TB) * 256 + t;
        if (i < 16384) {
            int k = i >> 7, c = i & 127;
            float w0 = W[i], w1 = W[16384 + i], w2 = W[32768 + i];
            WT[(size_t)c * 384 + k]       = f2bf(w0 - w2);
            WT[(size_t)c * 384 + 128 + k] = f2bf(w1);
            WT[(size_t)c * 384 + 256 + k] = f2bf(2.f * w2);
        }
    }
}

// ---- kernel 2: per-bucket CSR build + deg histogram (all LDS atomics) + cnt + dinv ----
__global__ __launch_bounds__(256) void k_csr(
        const int2* __restrict__ breg, const int* __restrict__ bcur,
        const int* __restrict__ sbreg, const int* __restrict__ sbcur,
        int REGCAP, int n,
        int* __restrict__ slots, int* __restrict__ cnt, float* __restrict__ dinv) {
    int b = blockIdx.x, t = threadIdx.x;
    __shared__ int c512[512], d512[512];
    c512[t] = 0; c512[t + 256] = 0;
    d512[t] = 0; d512[t + 256] = 0;
    __syncthreads();
    int M2 = sbcur[b]; if (M2 > REGCAP) M2 = REGCAP;
    const int* sreg = sbreg + (size_t)b * REGCAP;
    for (int idx = t; idx < M2; idx += 256)
        atomicAdd(&d512[sreg[idx] & 511], 1);
    int M = bcur[b]; if (M > REGCAP) M = REGCAP;
    const int2* reg = breg + (size_t)b * REGCAP;
    for (int idx = t; idx < M; idx += 256) {
        int2 e = reg[idx];
        int p = atomicAdd(&c512[e.y & 511], 1);
        if (p < CAP) slots[(size_t)e.y * CAP + p] = e.x;
    }
    __syncthreads();
    #pragma unroll
    for (int i = t; i < 512; i += 256) {
        int node = (b << 9) + i;
        if (node < n) {
            int c = c512[i];
            cnt[node] = c > CAP ? CAP : c;
            float dd = (float)d512[i];
            dinv[node] = dd > 0.f ? rsqrtf(dd) : 0.f;
        }
    }
}

// ---- kernel 3: lhat gather (j+=8, 2 gathers in flight per 16-lane group) ----
__global__ void k_gather_slots(const short* __restrict__ vbf, const int* __restrict__ cnt,
                               const int* __restrict__ slots, const float* __restrict__ dinv,
                               short* __restrict__ outp, int n) {
    int row = blockIdx.x * 4 + (threadIdx.x >> 6);
    if (row >= n) return;
    int lane = threadIdx.x & 63;
    int gr = lane >> 4, lc = lane & 15;
    int deg = cnt[row];
    bool vl = lane < deg;
    int   sl = vl ? slots[(size_t)row * CAP + lane] : 0;
    float wv = vl ? dinv[sl] : 0.f;
    float acc[8];
    #pragma unroll
    for (int t = 0; t < 8; ++t) acc[t] = 0.f;
    #pragma unroll 2
    for (int j = 0; j < deg; j += 8) {
        int j0 = j + gr, j1 = j + gr + 4;
        int   s0 = __shfl(sl, j0), s1 = __shfl(sl, j1);
        float w0 = __shfl(wv, j0), w1 = __shfl(wv, j1);
        short8 xv0 = *(const short8*)(vbf + (size_t)s0 * 128 + lc * 8);
        short8 xv1 = *(const short8*)(vbf + (size_t)s1 * 128 + lc * 8);
        #pragma unroll
        for (int t = 0; t < 8; ++t) {
            acc[t] = fmaf(w0, bf2f(xv0[t]), acc[t]);
            acc[t] = fmaf(w1, bf2f(xv1[t]), acc[t]);
        }
    }
    #pragma unroll
    for (int t = 0; t < 8; ++t) {
        acc[t] += __shfl_xor(acc[t], 32);
        acc[t] += __shfl_xor(acc[t], 16);
    }
    if (gr == 0) {
        float sc = -dinv[row];
        short8 o;
        #pragma unroll
        for (int t = 0; t < 8; ++t) o[t] = f2bf(sc * acc[t]);
        *(short8*)(outp + (size_t)row * 128 + lc * 8) = o;
    }
}

// ---- kernel 4: bf16 MFMA GEMM, BM=64; BN partials -> per-block stores ----
__global__ __launch_bounds__(256) void k_gemm_mfma(
        const short* __restrict__ A0bf, const short* __restrict__ A1bf,
        const short* __restrict__ A2bf,
        const short* __restrict__ WT, const float* __restrict__ bias,
        const float* __restrict__ aprelu, float* __restrict__ out,
        float* __restrict__ partials, int NB, int n) {
    __shared__ __align__(16) short Alds[64 * 64];
    __shared__ __align__(16) short Blds[128 * 64];

    int t = threadIdx.x;
    int lane = t & 63;
    int w = t >> 6;
    int wr = w >> 1, wc = w & 1;
    int row0 = blockIdx.x * 64;

    f32x4 acc[2][4];
    #pragma unroll
    for (int m = 0; m < 2; ++m)
        #pragma unroll
        for (int nn = 0; nn < 4; ++nn) acc[m][nn] = (f32x4){0.f, 0.f, 0.f, 0.f};

    #pragma unroll
    for (int ht = 0; ht < 6; ++ht) {
        const int h = ht >> 1, c = ht & 1;
        const short* Abf = (h == 0) ? A0bf : (h == 1) ? A1bf : A2bf;

        if (ht) __syncthreads();

        #pragma unroll
        for (int i = 0; i < 4; ++i) {
            int rB = w * 32 + i * 8 + (lane >> 3);
            int blkB = (lane & 7) ^ (rB & 7);
            const short* srcB = WT + (size_t)rB * 384 + h * 128 + c * 64 + blkB * 8;
            __builtin_amdgcn_global_load_lds(
                (const __attribute__((address_space(1))) void*)srcB,
                (__attribute__((address_space(3))) void*)&Blds[(w * 32 + i * 8) * 64],
                16, 0, 0);
        }
        #pragma unroll
        for (int i = 0; i < 2; ++i) {
            int rA = w * 16 + i * 8 + (lane >> 3);
            int grow = row0 + rA; if (grow >= n) grow = n - 1;
            int blkA = (lane & 7) ^ (rA & 7);
            const short* srcA = Abf + (size_t)grow * 128 + c * 64 + blkA * 8;
            __builtin_amdgcn_global_load_lds(
                (const __attribute__((address_space(1))) void*)srcA,
                (__attribute__((address_space(3))) void*)&Alds[(w * 16 + i * 8) * 64],
                16, 0, 0);
        }
        __syncthreads();

        #pragma unroll
        for (int kk = 0; kk < 2; ++kk) {
            short8 af[2], bfr[4];
            #pragma unroll
            for (int m = 0; m < 2; ++m) {
                int row = wr * 32 + m * 16 + (lane & 15);
                int blk = (kk * 4 + (lane >> 4)) ^ (row & 7);
                af[m] = *(const short8*)((const char*)Alds + row * 128 + blk * 16);
            }
            #pragma unroll
            for (int nn = 0; nn < 4; ++nn) {
                int col = wc * 64 + nn * 16 + (lane & 15);
                int blk = (kk * 4 + (lane >> 4)) ^ (col & 7);
                bfr[nn] = *(const short8*)((const char*)Blds + col * 128 + blk * 16);
            }
            #pragma unroll
            for (int m = 0; m < 2; ++m)
                #pragma unroll
                for (int nn = 0; nn < 4; ++nn)
                    acc[m][nn] = __builtin_amdgcn_mfma_f32_16x16x32_bf16(
                        af[m], bfr[nn], acc[m][nn], 0, 0, 0);
        }
    }

    __syncthreads();
    float* sred = (float*)Alds;      // [0..127]=sum, [128..255]=sumsq
    sred[t < 256 ? t : 0] = 0.f;
    __syncthreads();

    float ap = aprelu[0];
    #pragma unroll
    for (int nn = 0; nn < 4; ++nn) {
        int col = wc * 64 + nn * 16 + (lane & 15);
        float bs = bias[col];
        float s = 0.f, q = 0.f;
        #pragma unroll
        for (int m = 0; m < 2; ++m) {
            int rbase = row0 + wr * 32 + m * 16 + (lane >> 4) * 4;
            #pragma unroll
            for (int r = 0; r < 4; ++r) {
                int row = rbase + r;
                if (row < n) {
                    float o = acc[m][nn][r] + bs;
                    o = o >= 0.f ? o : ap * o;
                    out[(size_t)row * 128 + col] = o;
                    s += o; q = fmaf(o, o, q);
                }
            }
        }
        s += __shfl_xor(s, 16); s += __shfl_xor(s, 32);
        q += __shfl_xor(q, 16); q += __shfl_xor(q, 32);
        if ((lane >> 4) == 0) {
            atomicAdd(&sred[col], s);
            atomicAdd(&sred[128 + col], q);
        }
    }
    __syncthreads();
    if (t < 256) partials[(size_t)t * NB + blockIdx.x] = sred[t];
}

// ---- kernel 5: reduce partials -> sums/sumsq ----
__global__ __launch_bounds__(256) void k_redstats(
        const float* __restrict__ partials, int NB,
        float* __restrict__ sums, float* __restrict__ sumsq) {
    int j = blockIdx.x, t = threadIdx.x;
    const float* p = partials + (size_t)j * NB;
    float s = 0.f;
    for (int i = t; i < NB; i += 256) s += p[i];
    s += __shfl_xor(s, 1); s += __shfl_xor(s, 2); s += __shfl_xor(s, 4);
    s += __shfl_xor(s, 8); s += __shfl_xor(s, 16); s += __shfl_xor(s, 32);
    __shared__ float wsum[4];
    if ((t & 63) == 0) wsum[t >> 6] = s;
    __syncthreads();
    if (t == 0) {
        float tot = wsum[0] + wsum[1] + wsum[2] + wsum[3];
        if (j < 128) sums[j] = tot;
        else sumsq[j - 128] = tot;
    }
}

// ---- kernel 6: BN scale/shift from stats ----
__global__ void k_bnfinal(const float* __restrict__ sums, const float* __restrict__ sumsq,
                          const float* __restrict__ gamma, const float* __restrict__ beta,
                          float* __restrict__ bnp, float n) {
    int c = threadIdx.x;
    float mean = sums[c] / n;
    float var = sumsq[c] / n - mean * mean;
    float sc = gamma[c] * rsqrtf(var + EPS);
    bnp[c] = sc;
    bnp[128 + c] = beta[c] - mean * sc;
}

// ---- kernel 7: apply BN in place ----
__global__ void k_bnapply(float* __restrict__ out, const float* __restrict__ bnp, int total4) {
    int i = blockIdx.x * blockDim.x + threadIdx.x;
    if (i >= total4) return;
    float4 v = ((float4*)out)[i];
    int c = (i * 4) & 127;
    float4 sc = *(const float4*)&bnp[c];
    float4 sh = *(const float4*)&bnp[128 + c];
    v.x = fmaf(v.x, sc.x, sh.x);
    v.y = fmaf(v.y, sc.y, sh.y);
    v.z = fmaf(v.z, sc.z, sh.z);
    v.w = fmaf(v.w, sc.w, sh.w);
    ((float4*)out)[i] = v;
}

extern "C" void kernel_launch(void* const* d_in, const int* in_sizes, int n_in,
                              void* d_out, int out_size, void* d_ws, size_t ws_size,
                              hipStream_t stream) {
    const float* x      = (const float*)d_in[0];
    const int*   ei     = (const int*)d_in[1];
    const float* W      = (const float*)d_in[2];
    const float* bias   = (const float*)d_in[3];
    const float* aprelu = (const float*)d_in[4];
    const float* gamma  = (const float*)d_in[5];
    const float* beta   = (const float*)d_in[6];
    int n = in_sizes[0] / 128;
    int E = in_sizes[1] / 2;
    const int* srcp = ei;
    const int* dstp = ei + E;

    int NBK = (n + 511) >> 9;
    int REGCAP = ((E / NBK) * 2 + 255) & ~255;
    int mb = (n + 63) / 64;

    char* ws = (char*)d_ws;
    size_t off = 0;
    auto carve = [&](size_t bytes) {
        char* p = ws + off;
        off = (off + bytes + 511) & ~(size_t)511;
        return p;
    };
    short* xbf   = (short*)carve((size_t)n * 128 * 2);
    short* tx1bf = (short*)carve((size_t)n * 128 * 2);   // aliases sbreg (disjoint lifetime)
    int*   sbreg = (int*)tx1bf;
    size_t bregsz = (size_t)NBK * REGCAP * 8;
    size_t tx2sz  = (size_t)n * 128 * 2;
    char*  bregp  = carve(bregsz > tx2sz ? bregsz : tx2sz);
    int2*  breg   = (int2*)bregp;                        // live: k_prep..k_csr
    short* tx2bf  = (short*)bregp;                       // live: gather2..gemm (aliased)
    size_t zbeg = off;
    int*   bcur  = (int*)carve(NBMAX * 4);
    int*   sbcur = (int*)carve(NBMAX * 4);
    size_t zend = off;
    float* sums  = (float*)carve(512);
    float* sumsq = (float*)carve(512);
    float* dinv  = (float*)carve((size_t)n * 4);
    int*   cnt   = (int*)carve((size_t)n * 4);
    int*   slots = (int*)carve((size_t)n * CAP * 4);
    short* WT    = (short*)carve((size_t)128 * 384 * 2);
    float* bnp   = (float*)carve(256 * 4);
    float* partials = (float*)carve((size_t)256 * mb * 4);
    (void)ws_size; (void)n_in; (void)out_size;

    hipMemsetAsync(ws + zbeg, 0, zend - zbeg, stream);

    int BB = (E + CHUNK - 1) / CHUNK;
    int SB = BB;
    int t8 = n * 16;
    int TB = (t8 + 255) / 256;
    k_prep<<<BB + SB + TB + 64, 256, 0, stream>>>(srcp, dstp, E, x, W, bcur, breg,
                                                  sbcur, sbreg, REGCAP, NBK, xbf, WT,
                                                  BB, SB, TB, t8);
    k_csr<<<NBK, 256, 0, stream>>>(breg, bcur, sbreg, sbcur, REGCAP, n, slots, cnt, dinv);
    int gb = (n + 3) / 4;
    k_gather_slots<<<gb, 256, 0, stream>>>(xbf, cnt, slots, dinv, tx1bf, n);
    k_gather_slots<<<gb, 256, 0, stream>>>(tx1bf, cnt, slots, dinv, tx2bf, n);
    k_gemm_mfma<<<mb, 256, 0, stream>>>(xbf, tx1bf, tx2bf, WT, bias, aprelu, (float*)d_out,
                                        partials, mb, n);
    k_redstats<<<256, 256, 0, stream>>>(partials, mb, sums, sumsq);
    k_bnfinal<<<1, 128, 0, stream>>>(sums, sumsq, gamma, beta, bnp, (float)n);
    int total4 = n * 32;
    k_bnapply<<<(total4 + 255) / 256, 256, 0, stream>>>((float*)d_out, bnp, total4);
}